// Round 6
// baseline (952.411 us; speedup 1.0000x reference)
//
#include <hip/hip_runtime.h>
#include <hip/hip_bf16.h>

#define BW_   2048     // B * nW windows

typedef __attribute__((ext_vector_type(8))) short bf16x8;
typedef __attribute__((ext_vector_type(4))) float f32x4;

typedef __attribute__((address_space(1))) void gvoid;
typedef __attribute__((address_space(3))) void lvoid;

__device__ __forceinline__ void gload_lds16(const void* g, void* l) {
  __builtin_amdgcn_global_load_lds((gvoid*)g, (lvoid*)l, 16, 0, 0);
}

__device__ __forceinline__ float gelu_fast(float u) {
  // tanh-form GELU: u * sigmoid(1.5957691(u + 0.044715 u^3)); max err ~3e-4
  // hardware rcp instead of full-precision div (saves ~9 VALU instr/eval)
  const float t = u * u;
  const float c = __fmaf_rn(0.044715f * u, t, u);
  const float e = __expf(-1.5957691216057308f * c);
  return u * __builtin_amdgcn_rcpf(1.f + e);
}

// ---------------- weight pack: fp32 [K][N] -> bf16 [N][K] (B-transposed), qkv fused
__global__ __launch_bounds__(256) void k_pack(
    const float* __restrict__ wq, const float* __restrict__ wk,
    const float* __restrict__ wv, const float* __restrict__ wf1,
    const float* __restrict__ wf2, __hip_bfloat16* __restrict__ wqkvT,
    __hip_bfloat16* __restrict__ wf1T, __hip_bfloat16* __restrict__ wf2T)
{
  const int id = blockIdx.x * 256 + threadIdx.x;   // 720896 total
  if (id < 196608) {                     // wqkvT [768][256]
    const int n = id >> 8, kk = id & 255;
    const int sec = n >> 8, c = n & 255;
    const float* W = sec == 0 ? wq : (sec == 1 ? wk : wv);
    wqkvT[id] = __float2bfloat16(W[kk * 256 + c]);
  } else if (id < 458752) {              // wf1T [1024][256]
    const int t = id - 196608;
    const int n = t >> 8, kk = t & 255;
    wf1T[t] = __float2bfloat16(wf1[kk * 1024 + n]);
  } else {                               // wf2T [256][1024]
    const int t = id - 458752;
    const int n = t >> 10, kk = t & 1023;
    wf2T[t] = __float2bfloat16(wf2[kk * 256 + n]);
  }
}

// ---------------- rel-pos bias gather: biasPre[nh][n][m]
__global__ __launch_bounds__(256) void k_bias_pre(
    const float* __restrict__ table, float* __restrict__ biasPre)
{
  const int idx = blockIdx.x * 256 + threadIdx.x;  // 32768
  const int nh = idx >> 12, n = (idx >> 6) & 63, m = idx & 63;
  const int dr = (n >> 3) - (m >> 3) + 7, dc = (n & 7) - (m & 7) + 7;
  biasPre[idx] = table[(dr * 15 + dc) * 8 + nh];
}

// ---------------- fused LN1 + roll + window + QKV GEMM (N=768 looped)
// out: q/k head layout [win][nh][tok][32], v transposed [win][nh][32][tok]
// Alds swizzle: 8-slot XOR (elem ^= (row&7)<<3) -> conflict-free ds_read_b128
__global__ __launch_bounds__(256, 2) void k_qkv(
    const float* __restrict__ x, const float* __restrict__ g1,
    const float* __restrict__ b1, const __hip_bfloat16* __restrict__ wqkvT,
    const float* __restrict__ bq, const float* __restrict__ bk,
    const float* __restrict__ bv, __hip_bfloat16* __restrict__ qb,
    __hip_bfloat16* __restrict__ kbuf, __hip_bfloat16* __restrict__ vtb)
{
  __shared__ __align__(16) __hip_bfloat16 Alds[128 * 256];   // 64KB, swizzled
  const int tid = threadIdx.x, wid = tid >> 6, lane = tid & 63;
  const int quad = lane >> 4, ln = lane & 15;
  const int mtile = blockIdx.x * 128;

  // ---- LN1 stage: each wave 32 tokens, write bf16 into swizzled Alds
  #pragma unroll 4
  for (int i = 0; i < 32; i++) {
    const int tl = wid * 32 + i;
    const int row = mtile + tl;
    const int win = row >> 6, n = row & 63;
    const int b = win >> 10, wimg = win & 1023, wi = wimg >> 5, wj = wimg & 31;
    const int y = (wi * 8 + (n >> 3) + 4) & 255, xc = (wj * 8 + (n & 7) + 4) & 255;
    float4 v = ((const float4*)(x + ((size_t)(b * 65536 + y * 256 + xc)) * 256))[lane];
    float s  = v.x + v.y + v.z + v.w;
    float sq = v.x*v.x + v.y*v.y + v.z*v.z + v.w*v.w;
    for (int o = 32; o > 0; o >>= 1) { s += __shfl_xor(s, o); sq += __shfl_xor(sq, o); }
    const float mean = s * (1.f/256.f);
    const float rstd = rsqrtf(sq * (1.f/256.f) - mean*mean + 1e-5f);
    const int c0 = lane * 4;
    float vv[4] = {v.x, v.y, v.z, v.w};
    union { __hip_bfloat16 h[4]; uint2 u; } ob;
    #pragma unroll
    for (int jj = 0; jj < 4; jj++)
      ob.h[jj] = __float2bfloat16((vv[jj]-mean)*rstd*g1[c0+jj] + b1[c0+jj]);
    *(uint2*)&Alds[tl*256 + (c0 ^ ((tl & 7) << 3))] = ob.u;
  }
  __syncthreads();

  const int wrow = (wid >> 1) * 64, wcol = (wid & 1) * 64;
  for (int nb = 0; nb < 6; nb++) {
    f32x4 acc[4][4];
    #pragma unroll
    for (int mt = 0; mt < 4; mt++)
      #pragma unroll
      for (int nt = 0; nt < 4; nt++) acc[mt][nt] = (f32x4){0.f,0.f,0.f,0.f};
    #pragma unroll
    for (int k0 = 0; k0 < 256; k0 += 32) {
      bf16x8 af[4], bfr[4];
      #pragma unroll
      for (int mt = 0; mt < 4; mt++) {
        const int r = wrow + mt*16 + ln;
        af[mt] = *(const bf16x8*)&Alds[r*256 + ((k0 + (quad<<3)) ^ ((r & 7) << 3))];
      }
      #pragma unroll
      for (int nt = 0; nt < 4; nt++) {
        const int nn = nb*128 + wcol + nt*16 + ln;
        bfr[nt] = *(const bf16x8*)(wqkvT + (size_t)nn*256 + k0 + quad*8);
      }
      #pragma unroll
      for (int mt = 0; mt < 4; mt++)
        #pragma unroll
        for (int nt = 0; nt < 4; nt++)
          acc[mt][nt] = __builtin_amdgcn_mfma_f32_16x16x32_bf16(af[mt], bfr[nt], acc[mt][nt], 0, 0, 0);
    }
    // epilogue: scatter to q/k (head layout) or vt (transposed)
    #pragma unroll
    for (int mt = 0; mt < 4; mt++) {
      #pragma unroll
      for (int nt = 0; nt < 4; nt++) {
        const int cB = nb*128 + wcol + nt*16 + ln;
        const int sec = cB >> 8, c = cB & 255, nh = c >> 5, d = c & 31;
        const float bs = (sec == 0 ? bq : (sec == 1 ? bk : bv))[c];
        #pragma unroll
        for (int r = 0; r < 4; r++) {
          const int mB = mtile + wrow + mt*16 + quad*4 + r;
          const int win = mB >> 6, tok = mB & 63;
          const __hip_bfloat16 hv = __float2bfloat16(acc[mt][nt][r] + bs);
          if (sec < 2) {
            __hip_bfloat16* dst = sec == 0 ? qb : kbuf;
            dst[(((size_t)win*8 + nh)*64 + tok)*32 + d] = hv;
          } else {
            vtb[(((size_t)win*8 + nh)*32 + d)*64 + tok] = hv;
          }
        }
      }
    }
  }
}

// ---------------- fused attention + un-window(scramble) + residual + LN2 -> zb
// block=256 (4 waves) per window; wave wv computes heads 2wv,2wv+1 which are
// exactly the heads its 16 output pixels need (head = y2 & 7) -> no barriers.
__global__ __launch_bounds__(256, 2) void k_attn2(
    const __hip_bfloat16* __restrict__ q, const __hip_bfloat16* __restrict__ kbuf,
    const __hip_bfloat16* __restrict__ vt, const float* __restrict__ biasPre,
    const float* __restrict__ x, const float* __restrict__ g2,
    const float* __restrict__ b2, __hip_bfloat16* __restrict__ zb)
{
  __shared__ __align__(16) __hip_bfloat16 Plds[4][64*72];    // 36KB
  __shared__ __align__(16) __hip_bfloat16 Olds[4][2][64*36]; // 36KB
  const int tid = threadIdx.x, wv = tid >> 6, lane = tid & 63;
  const int quad = lane >> 4, ln = lane & 15;
  const int win = blockIdx.x;
  const int b = win >> 10, wimg = win & 1023, wi = wimg >> 5, wj = wimg & 31;

  int colreg[4], rowreg[4][4];
  #pragma unroll
  for (int nt = 0; nt < 4; nt++) {
    const int t = nt*16 + ln;
    const int y = wi*8 + (t >> 3), xx = wj*8 + (t & 7);
    colreg[nt] = ((y < 248) ? 0 : ((y < 252) ? 1 : 2)) * 3 +
                 ((xx < 248) ? 0 : ((xx < 252) ? 1 : 2));
  }
  #pragma unroll
  for (int mt = 0; mt < 4; mt++)
    #pragma unroll
    for (int r = 0; r < 4; r++) {
      const int t = mt*16 + quad*4 + r;
      const int y = wi*8 + (t >> 3), xx = wj*8 + (t & 7);
      rowreg[mt][r] = ((y < 248) ? 0 : ((y < 252) ? 1 : 2)) * 3 +
                      ((xx < 248) ? 0 : ((xx < 252) ? 1 : 2));
    }

  #pragma unroll
  for (int hh = 0; hh < 2; hh++) {
    const int h = wv*2 + hh;
    const size_t base = ((size_t)win*8 + h)*2048;

    bf16x8 af[4], bfr[4];
    #pragma unroll
    for (int mt = 0; mt < 4; mt++)
      af[mt] = *(const bf16x8*)(q + base + (size_t)(mt*16 + ln)*32 + quad*8);
    #pragma unroll
    for (int nt = 0; nt < 4; nt++)
      bfr[nt] = *(const bf16x8*)(kbuf + base + (size_t)(nt*16 + ln)*32 + quad*8);
    f32x4 s[4][4];
    #pragma unroll
    for (int mt = 0; mt < 4; mt++)
      #pragma unroll
      for (int nt = 0; nt < 4; nt++) {
        s[mt][nt] = (f32x4){0.f,0.f,0.f,0.f};
        s[mt][nt] = __builtin_amdgcn_mfma_f32_16x16x32_bf16(af[mt], bfr[nt], s[mt][nt], 0, 0, 0);
      }

    const float* bp = biasPre + (h << 12);
    #pragma unroll
    for (int mt = 0; mt < 4; mt++)
      #pragma unroll
      for (int nt = 0; nt < 4; nt++)
        #pragma unroll
        for (int r = 0; r < 4; r++) {
          const int row = mt*16 + quad*4 + r, col = nt*16 + ln;
          float val = s[mt][nt][r] * 0.17677669529663687f + bp[row*64 + col];
          if (rowreg[mt][r] != colreg[nt]) val -= 100.f;
          s[mt][nt][r] = val;
        }

    #pragma unroll
    for (int mt = 0; mt < 4; mt++) {
      f32x4 mx;
      #pragma unroll
      for (int r = 0; r < 4; r++)
        mx[r] = fmaxf(fmaxf(s[mt][0][r], s[mt][1][r]), fmaxf(s[mt][2][r], s[mt][3][r]));
      #pragma unroll
      for (int msk = 1; msk <= 8; msk <<= 1)
        #pragma unroll
        for (int r = 0; r < 4; r++) mx[r] = fmaxf(mx[r], __shfl_xor(mx[r], msk));
      f32x4 sum = (f32x4){0.f,0.f,0.f,0.f};
      #pragma unroll
      for (int nt = 0; nt < 4; nt++)
        #pragma unroll
        for (int r = 0; r < 4; r++) {
          s[mt][nt][r] = __expf(s[mt][nt][r] - mx[r]);
          sum[r] += s[mt][nt][r];
        }
      #pragma unroll
      for (int msk = 1; msk <= 8; msk <<= 1)
        #pragma unroll
        for (int r = 0; r < 4; r++) sum[r] += __shfl_xor(sum[r], msk);
      f32x4 rs;
      #pragma unroll
      for (int r = 0; r < 4; r++) rs[r] = __builtin_amdgcn_rcpf(sum[r]);
      #pragma unroll
      for (int nt = 0; nt < 4; nt++)
        #pragma unroll
        for (int r = 0; r < 4; r++)
          Plds[wv][(mt*16 + quad*4 + r)*72 + nt*16 + ln] =
              __float2bfloat16(s[mt][nt][r] * rs[r]);
    }

    f32x4 o[4][2];
    #pragma unroll
    for (int mt = 0; mt < 4; mt++)
      #pragma unroll
      for (int dt = 0; dt < 2; dt++) o[mt][dt] = (f32x4){0.f,0.f,0.f,0.f};
    #pragma unroll
    for (int ks = 0; ks < 2; ks++) {
      bf16x8 pa[4];
      #pragma unroll
      for (int mt = 0; mt < 4; mt++)
        pa[mt] = *(const bf16x8*)&Plds[wv][(mt*16 + ln)*72 + ks*32 + quad*8];
      #pragma unroll
      for (int dt = 0; dt < 2; dt++) {
        const bf16x8 vb = *(const bf16x8*)(vt + base + (size_t)(dt*16 + ln)*64 + ks*32 + quad*8);
        #pragma unroll
        for (int mt = 0; mt < 4; mt++)
          o[mt][dt] = __builtin_amdgcn_mfma_f32_16x16x32_bf16(pa[mt], vb, o[mt][dt], 0, 0, 0);
      }
    }
    #pragma unroll
    for (int mt = 0; mt < 4; mt++)
      #pragma unroll
      for (int dt = 0; dt < 2; dt++)
        #pragma unroll
        for (int r = 0; r < 4; r++)
          Olds[wv][hh][(mt*16 + quad*4 + r)*36 + dt*16 + ln] =
              __float2bfloat16(o[mt][dt][r]);
  }

  // ---- per-wave LN2 over its 16 output pixels (heads 2wv,2wv+1 local)
  #pragma unroll 4
  for (int i = 0; i < 16; i++) {
    const int p = wv*16 + i, py = p >> 3, px = p & 7, hh = i >> 3;
    const int y2 = wi*8 + py, x2 = wj*8 + px;
    const int y = (y2 + 4) & 255, xx = (x2 + 4) & 255;
    const size_t t = (size_t)b*65536 + y*256 + xx;
    const int c0 = lane * 4;
    const int nn = px*8 + (c0 >> 5), d = c0 & 31;
    union { __hip_bfloat16 h[4]; uint2 u; } ou;
    ou.u = *(const uint2*)&Olds[wv][hh][nn*36 + d];
    float4 xv = ((const float4*)(x + t*256))[lane];
    float sv[4];
    sv[0] = xv.x + __bfloat162float(ou.h[0]);
    sv[1] = xv.y + __bfloat162float(ou.h[1]);
    sv[2] = xv.z + __bfloat162float(ou.h[2]);
    sv[3] = xv.w + __bfloat162float(ou.h[3]);
    float s  = sv[0]+sv[1]+sv[2]+sv[3];
    float sq = sv[0]*sv[0]+sv[1]*sv[1]+sv[2]*sv[2]+sv[3]*sv[3];
    for (int o = 32; o > 0; o >>= 1) { s += __shfl_xor(s, o); sq += __shfl_xor(sq, o); }
    const float mean = s*(1.f/256.f);
    const float rstd = rsqrtf(sq*(1.f/256.f) - mean*mean + 1e-5f);
    union { __hip_bfloat16 h[4]; uint2 u; } ob;
    #pragma unroll
    for (int jj = 0; jj < 4; jj++)
      ob.h[jj] = __float2bfloat16((sv[jj]-mean)*rstd*g2[c0+jj] + b2[c0+jj]);
    *(uint2*)(zb + t*256 + c0) = ob.u;
  }
}

// ---------------- fused MLP: FC1 -> GELU -> FC2 (+bias +zb residual) -> d_out fp32
// 64-token blocks; hidden chunk 128 (8 iters), FC1 wave tile 4x2, FC2 4x4.
// Z is NOT LDS-staged: the 32KB Z-panel is shared by all 4 waves and re-read
// 8x -> it lives in L1. FC1 A-fragments read directly from global (16 rows x
// 64B contiguous per bf16x8 load = fully line-coalesced). Removes the staging
// phase + barrier, halves LDS-port pressure, LDS 48->16KB.
// H [64x128] single-buffer, 8-slot XOR swizzle (conflict-free b128 reads).
// launch_bounds(256,2): (256,3) capped VGPR at 84 -> acc2 spilled to scratch
// (+105MB WRITE, dur 322->397). Keep 2. [round-2 lesson]
// Round-4 lesson: merged FC1||FC2 inter-barrier region regressed (310->344);
// keep the simple {FC1; Hwrite; bar; FC2; bar} phase structure.
__global__ __launch_bounds__(256, 2) void k_mlp(
    const __hip_bfloat16* __restrict__ zb, const __hip_bfloat16* __restrict__ wf1T,
    const __hip_bfloat16* __restrict__ wf2T, const float* __restrict__ bf1,
    const float* __restrict__ bf2, float* __restrict__ out)
{
  __shared__ __align__(16) __hip_bfloat16 Hlds[64 * 128];   // 16KB, swizzled
  const int tid = threadIdx.x, w = tid >> 6, lane = tid & 63;
  const int quad = lane >> 4, ln = lane & 15;
  const int m0 = blockIdx.x * 64;

  f32x4 acc2[4][4];
  #pragma unroll
  for (int mt = 0; mt < 4; mt++)
    #pragma unroll
    for (int nt = 0; nt < 4; nt++) acc2[mt][nt] = (f32x4){0.f,0.f,0.f,0.f};

  for (int hc = 0; hc < 8; hc++) {
    // ---- FC1 chunk: H[64 x 128], wave w computes hidden cols [w*32, w*32+32)
    // A (Z) direct from global: L1-resident 32KB panel, no LDS round-trip.
    f32x4 a1[4][2];
    #pragma unroll
    for (int mt = 0; mt < 4; mt++)
      #pragma unroll
      for (int nt = 0; nt < 2; nt++) a1[mt][nt] = (f32x4){0.f,0.f,0.f,0.f};
    #pragma unroll
    for (int k0 = 0; k0 < 256; k0 += 32) {
      bf16x8 za[4], b1f[2];
      #pragma unroll
      for (int mt = 0; mt < 4; mt++)
        za[mt] = *(const bf16x8*)(zb + (size_t)(m0 + mt*16 + ln)*256 + k0 + quad*8);
      #pragma unroll
      for (int nt = 0; nt < 2; nt++) {
        const int n1 = hc*128 + w*32 + nt*16 + ln;
        b1f[nt] = *(const bf16x8*)(wf1T + (size_t)n1*256 + k0 + quad*8);
      }
      #pragma unroll
      for (int mt = 0; mt < 4; mt++)
        #pragma unroll
        for (int nt = 0; nt < 2; nt++)
          a1[mt][nt] = __builtin_amdgcn_mfma_f32_16x16x32_bf16(za[mt], b1f[nt], a1[mt][nt], 0, 0, 0);
    }
    // GELU + swizzled Hlds write
    #pragma unroll
    for (int mt = 0; mt < 4; mt++)
      #pragma unroll
      for (int nt = 0; nt < 2; nt++) {
        const int n = w*32 + nt*16 + ln;
        const float bs = bf1[hc*128 + n];
        #pragma unroll
        for (int r = 0; r < 4; r++) {
          const int m1 = mt*16 + quad*4 + r;
          const float u = gelu_fast(a1[mt][nt][r] + bs);
          Hlds[m1*128 + (n ^ ((m1 & 7) << 3))] = __float2bfloat16(u);
        }
      }
    __syncthreads();
    // ---- FC2 partial: out[64 x 256] += H @ wf2T_chunk, wave w cols [w*64,+64)
    #pragma unroll
    for (int ks = 0; ks < 4; ks++) {
      bf16x8 ha[4];
      #pragma unroll
      for (int mt = 0; mt < 4; mt++) {
        const int m = mt*16 + ln;
        ha[mt] = *(const bf16x8*)&Hlds[m*128 + ((ks*32 + (quad<<3)) ^ ((m & 7) << 3))];
      }
      #pragma unroll
      for (int nt = 0; nt < 4; nt++) {
        const int n2 = w*64 + nt*16 + ln;
        const bf16x8 b2f = *(const bf16x8*)(wf2T + (size_t)n2*1024 + hc*128 + ks*32 + quad*8);
        #pragma unroll
        for (int mt = 0; mt < 4; mt++)
          acc2[mt][nt] = __builtin_amdgcn_mfma_f32_16x16x32_bf16(ha[mt], b2f, acc2[mt][nt], 0, 0, 0);
      }
    }
    __syncthreads();
  }

  // epilogue: + bias + zb residual (L1-hot), fp32 out
  #pragma unroll
  for (int mt = 0; mt < 4; mt++) {
    #pragma unroll
    for (int nt = 0; nt < 4; nt++) {
      const int cB = w*64 + nt*16 + ln;
      const float bs = bf2[cB];
      #pragma unroll
      for (int r = 0; r < 4; r++) {
        const int tok = mt*16 + quad*4 + r;
        const float res = __bfloat162float(zb[(size_t)(m0 + tok)*256 + cB]);
        out[(size_t)(m0 + tok)*256 + cB] = acc2[mt][nt][r] + bs + res;
      }
    }
  }
}

extern "C" void kernel_launch(void* const* d_in, const int* in_sizes, int n_in,
                              void* d_out, int out_size, void* d_ws, size_t ws_size,
                              hipStream_t stream)
{
  (void)in_sizes; (void)n_in; (void)out_size; (void)ws_size;
  const float* x   = (const float*)d_in[0];
  const float* g1  = (const float*)d_in[1];
  const float* b1  = (const float*)d_in[2];
  const float* wq  = (const float*)d_in[3];
  const float* bq  = (const float*)d_in[4];
  const float* wk  = (const float*)d_in[5];
  const float* bk  = (const float*)d_in[6];
  const float* wv  = (const float*)d_in[7];
  const float* bv  = (const float*)d_in[8];
  const float* tbl = (const float*)d_in[9];
  const float* g2  = (const float*)d_in[10];
  const float* b2  = (const float*)d_in[11];
  const float* wf1 = (const float*)d_in[12];
  const float* bf1 = (const float*)d_in[13];
  const float* wf2 = (const float*)d_in[14];
  const float* bf2 = (const float*)d_in[15];

  char* ws = (char*)d_ws;
  const size_t MB = 1024ull*1024ull;
  __hip_bfloat16* qb    = (__hip_bfloat16*)(ws);             // 64MB
  __hip_bfloat16* kb    = (__hip_bfloat16*)(ws + 64*MB);     // 64MB
  __hip_bfloat16* vtb   = (__hip_bfloat16*)(ws + 128*MB);    // 64MB
  __hip_bfloat16* zb    = (__hip_bfloat16*)(ws + 192*MB);    // 64MB
  float*          biasP = (float*)(ws + 256*MB);             // 128KB
  __hip_bfloat16* wqkvT = (__hip_bfloat16*)(ws + 257*MB);    // 384KB
  __hip_bfloat16* wf1T  = (__hip_bfloat16*)(ws + 258*MB);    // 512KB
  __hip_bfloat16* wf2T  = (__hip_bfloat16*)(ws + 259*MB);    // 512KB

  k_pack<<<2816, 256, 0, stream>>>(wq, wk, wv, wf1, wf2, wqkvT, wf1T, wf2T);
  k_bias_pre<<<128, 256, 0, stream>>>(tbl, biasP);
  k_qkv<<<1024, 256, 0, stream>>>(x, g1, b1, wqkvT, bq, bk, bv, qb, kb, vtb);
  k_attn2<<<BW_, 256, 0, stream>>>(qb, kb, vtb, biasP, x, g2, b2, zb);
  k_mlp<<<2048, 256, 0, stream>>>(zb, wf1T, wf2T, bf1, bf2, (float*)d_out);
}

// Round 7
// 751.172 us; speedup vs baseline: 1.2679x; 1.2679x over previous
//
#include <hip/hip_runtime.h>
#include <hip/hip_bf16.h>

#define BW_   2048     // B * nW windows

typedef __attribute__((ext_vector_type(8))) short bf16x8;
typedef __attribute__((ext_vector_type(4))) float f32x4;

typedef __attribute__((address_space(1))) void gvoid;
typedef __attribute__((address_space(3))) void lvoid;

__device__ __forceinline__ void gload_lds16(const void* g, void* l) {
  __builtin_amdgcn_global_load_lds((gvoid*)g, (lvoid*)l, 16, 0, 0);
}

__device__ __forceinline__ float gelu_fast(float u) {
  // tanh-form GELU: u * sigmoid(1.5957691(u + 0.044715 u^3)); max err ~3e-4
  // hardware rcp instead of full-precision div (saves ~9 VALU instr/eval)
  const float t = u * u;
  const float c = __fmaf_rn(0.044715f * u, t, u);
  const float e = __expf(-1.5957691216057308f * c);
  return u * __builtin_amdgcn_rcpf(1.f + e);
}

// ---------------- weight pack: fp32 [K][N] -> bf16 [N][K] (B-transposed), qkv fused
__global__ __launch_bounds__(256) void k_pack(
    const float* __restrict__ wq, const float* __restrict__ wk,
    const float* __restrict__ wv, const float* __restrict__ wf1,
    const float* __restrict__ wf2, __hip_bfloat16* __restrict__ wqkvT,
    __hip_bfloat16* __restrict__ wf1T, __hip_bfloat16* __restrict__ wf2T)
{
  const int id = blockIdx.x * 256 + threadIdx.x;   // 720896 total
  if (id < 196608) {                     // wqkvT [768][256]
    const int n = id >> 8, kk = id & 255;
    const int sec = n >> 8, c = n & 255;
    const float* W = sec == 0 ? wq : (sec == 1 ? wk : wv);
    wqkvT[id] = __float2bfloat16(W[kk * 256 + c]);
  } else if (id < 458752) {              // wf1T [1024][256]
    const int t = id - 196608;
    const int n = t >> 8, kk = t & 255;
    wf1T[t] = __float2bfloat16(wf1[kk * 1024 + n]);
  } else {                               // wf2T [256][1024]
    const int t = id - 458752;
    const int n = t >> 10, kk = t & 1023;
    wf2T[t] = __float2bfloat16(wf2[kk * 256 + n]);
  }
}

// ---------------- rel-pos bias gather: biasPre[nh][n][m]
__global__ __launch_bounds__(256) void k_bias_pre(
    const float* __restrict__ table, float* __restrict__ biasPre)
{
  const int idx = blockIdx.x * 256 + threadIdx.x;  // 32768
  const int nh = idx >> 12, n = (idx >> 6) & 63, m = idx & 63;
  const int dr = (n >> 3) - (m >> 3) + 7, dc = (n & 7) - (m & 7) + 7;
  biasPre[idx] = table[(dr * 15 + dc) * 8 + nh];
}

// ---------------- fused LN1 + roll + window + QKV GEMM (N=768 looped)
// out: q/k head layout [win][nh][tok][32], v transposed [win][nh][32][tok]
// Alds swizzle: 8-slot XOR (elem ^= (row&7)<<3) -> conflict-free ds_read_b128
// vtb epilogue: 4 consecutive tokens at fixed d -> packed uint2 store (8B).
__global__ __launch_bounds__(256, 2) void k_qkv(
    const float* __restrict__ x, const float* __restrict__ g1,
    const float* __restrict__ b1, const __hip_bfloat16* __restrict__ wqkvT,
    const float* __restrict__ bq, const float* __restrict__ bk,
    const float* __restrict__ bv, __hip_bfloat16* __restrict__ qb,
    __hip_bfloat16* __restrict__ kbuf, __hip_bfloat16* __restrict__ vtb)
{
  __shared__ __align__(16) __hip_bfloat16 Alds[128 * 256];   // 64KB, swizzled
  const int tid = threadIdx.x, wid = tid >> 6, lane = tid & 63;
  const int quad = lane >> 4, ln = lane & 15;
  const int mtile = blockIdx.x * 128;

  // ---- LN1 stage: each wave 32 tokens, write bf16 into swizzled Alds
  #pragma unroll 4
  for (int i = 0; i < 32; i++) {
    const int tl = wid * 32 + i;
    const int row = mtile + tl;
    const int win = row >> 6, n = row & 63;
    const int b = win >> 10, wimg = win & 1023, wi = wimg >> 5, wj = wimg & 31;
    const int y = (wi * 8 + (n >> 3) + 4) & 255, xc = (wj * 8 + (n & 7) + 4) & 255;
    float4 v = ((const float4*)(x + ((size_t)(b * 65536 + y * 256 + xc)) * 256))[lane];
    float s  = v.x + v.y + v.z + v.w;
    float sq = v.x*v.x + v.y*v.y + v.z*v.z + v.w*v.w;
    for (int o = 32; o > 0; o >>= 1) { s += __shfl_xor(s, o); sq += __shfl_xor(sq, o); }
    const float mean = s * (1.f/256.f);
    const float rstd = rsqrtf(sq * (1.f/256.f) - mean*mean + 1e-5f);
    const int c0 = lane * 4;
    float vv[4] = {v.x, v.y, v.z, v.w};
    union { __hip_bfloat16 h[4]; uint2 u; } ob;
    #pragma unroll
    for (int jj = 0; jj < 4; jj++)
      ob.h[jj] = __float2bfloat16((vv[jj]-mean)*rstd*g1[c0+jj] + b1[c0+jj]);
    *(uint2*)&Alds[tl*256 + (c0 ^ ((tl & 7) << 3))] = ob.u;
  }
  __syncthreads();

  const int wrow = (wid >> 1) * 64, wcol = (wid & 1) * 64;
  for (int nb = 0; nb < 6; nb++) {
    f32x4 acc[4][4];
    #pragma unroll
    for (int mt = 0; mt < 4; mt++)
      #pragma unroll
      for (int nt = 0; nt < 4; nt++) acc[mt][nt] = (f32x4){0.f,0.f,0.f,0.f};
    #pragma unroll
    for (int k0 = 0; k0 < 256; k0 += 32) {
      bf16x8 af[4], bfr[4];
      #pragma unroll
      for (int mt = 0; mt < 4; mt++) {
        const int r = wrow + mt*16 + ln;
        af[mt] = *(const bf16x8*)&Alds[r*256 + ((k0 + (quad<<3)) ^ ((r & 7) << 3))];
      }
      #pragma unroll
      for (int nt = 0; nt < 4; nt++) {
        const int nn = nb*128 + wcol + nt*16 + ln;
        bfr[nt] = *(const bf16x8*)(wqkvT + (size_t)nn*256 + k0 + quad*8);
      }
      #pragma unroll
      for (int mt = 0; mt < 4; mt++)
        #pragma unroll
        for (int nt = 0; nt < 4; nt++)
          acc[mt][nt] = __builtin_amdgcn_mfma_f32_16x16x32_bf16(af[mt], bfr[nt], acc[mt][nt], 0, 0, 0);
    }
    // epilogue: scatter to q/k (head layout) or vt (transposed, packed stores)
    #pragma unroll
    for (int mt = 0; mt < 4; mt++) {
      #pragma unroll
      for (int nt = 0; nt < 4; nt++) {
        const int cB = nb*128 + wcol + nt*16 + ln;
        const int sec = cB >> 8, c = cB & 255, nh = c >> 5, d = c & 31;
        const float bs = (sec == 0 ? bq : (sec == 1 ? bk : bv))[c];
        if (sec < 2) {
          __hip_bfloat16* dst = sec == 0 ? qb : kbuf;
          #pragma unroll
          for (int r = 0; r < 4; r++) {
            const int mB = mtile + wrow + mt*16 + quad*4 + r;
            const int win = mB >> 6, tok = mB & 63;
            dst[(((size_t)win*8 + nh)*64 + tok)*32 + d] =
                __float2bfloat16(acc[mt][nt][r] + bs);
          }
        } else {
          // 4 r-values are 4 consecutive tokens at fixed d -> one 8B store
          const int mB0 = mtile + wrow + mt*16 + quad*4;
          const int win = mB0 >> 6, tok0 = mB0 & 63;
          union { __hip_bfloat16 h[4]; uint2 u; } pv;
          #pragma unroll
          for (int r = 0; r < 4; r++)
            pv.h[r] = __float2bfloat16(acc[mt][nt][r] + bs);
          *(uint2*)(vtb + (((size_t)win*8 + nh)*32 + d)*64 + tok0) = pv.u;
        }
      }
    }
  }
}

// ---------------- fused attention + un-window(scramble) + residual + LN2 -> zb
// block=256 (4 waves) per window; wave wv computes heads 2wv,2wv+1 which are
// exactly the heads its 16 output pixels need (head = y2 & 7) -> no barriers.
__global__ __launch_bounds__(256, 2) void k_attn2(
    const __hip_bfloat16* __restrict__ q, const __hip_bfloat16* __restrict__ kbuf,
    const __hip_bfloat16* __restrict__ vt, const float* __restrict__ biasPre,
    const float* __restrict__ x, const float* __restrict__ g2,
    const float* __restrict__ b2, __hip_bfloat16* __restrict__ zb)
{
  __shared__ __align__(16) __hip_bfloat16 Plds[4][64*72];    // 36KB
  __shared__ __align__(16) __hip_bfloat16 Olds[4][2][64*36]; // 36KB
  const int tid = threadIdx.x, wv = tid >> 6, lane = tid & 63;
  const int quad = lane >> 4, ln = lane & 15;
  const int win = blockIdx.x;
  const int b = win >> 10, wimg = win & 1023, wi = wimg >> 5, wj = wimg & 31;

  int colreg[4], rowreg[4][4];
  #pragma unroll
  for (int nt = 0; nt < 4; nt++) {
    const int t = nt*16 + ln;
    const int y = wi*8 + (t >> 3), xx = wj*8 + (t & 7);
    colreg[nt] = ((y < 248) ? 0 : ((y < 252) ? 1 : 2)) * 3 +
                 ((xx < 248) ? 0 : ((xx < 252) ? 1 : 2));
  }
  #pragma unroll
  for (int mt = 0; mt < 4; mt++)
    #pragma unroll
    for (int r = 0; r < 4; r++) {
      const int t = mt*16 + quad*4 + r;
      const int y = wi*8 + (t >> 3), xx = wj*8 + (t & 7);
      rowreg[mt][r] = ((y < 248) ? 0 : ((y < 252) ? 1 : 2)) * 3 +
                      ((xx < 248) ? 0 : ((xx < 252) ? 1 : 2));
    }

  #pragma unroll
  for (int hh = 0; hh < 2; hh++) {
    const int h = wv*2 + hh;
    const size_t base = ((size_t)win*8 + h)*2048;

    bf16x8 af[4], bfr[4];
    #pragma unroll
    for (int mt = 0; mt < 4; mt++)
      af[mt] = *(const bf16x8*)(q + base + (size_t)(mt*16 + ln)*32 + quad*8);
    #pragma unroll
    for (int nt = 0; nt < 4; nt++)
      bfr[nt] = *(const bf16x8*)(kbuf + base + (size_t)(nt*16 + ln)*32 + quad*8);
    f32x4 s[4][4];
    #pragma unroll
    for (int mt = 0; mt < 4; mt++)
      #pragma unroll
      for (int nt = 0; nt < 4; nt++) {
        s[mt][nt] = (f32x4){0.f,0.f,0.f,0.f};
        s[mt][nt] = __builtin_amdgcn_mfma_f32_16x16x32_bf16(af[mt], bfr[nt], s[mt][nt], 0, 0, 0);
      }

    const float* bp = biasPre + (h << 12);
    #pragma unroll
    for (int mt = 0; mt < 4; mt++)
      #pragma unroll
      for (int nt = 0; nt < 4; nt++)
        #pragma unroll
        for (int r = 0; r < 4; r++) {
          const int row = mt*16 + quad*4 + r, col = nt*16 + ln;
          float val = s[mt][nt][r] * 0.17677669529663687f + bp[row*64 + col];
          if (rowreg[mt][r] != colreg[nt]) val -= 100.f;
          s[mt][nt][r] = val;
        }

    #pragma unroll
    for (int mt = 0; mt < 4; mt++) {
      f32x4 mx;
      #pragma unroll
      for (int r = 0; r < 4; r++)
        mx[r] = fmaxf(fmaxf(s[mt][0][r], s[mt][1][r]), fmaxf(s[mt][2][r], s[mt][3][r]));
      #pragma unroll
      for (int msk = 1; msk <= 8; msk <<= 1)
        #pragma unroll
        for (int r = 0; r < 4; r++) mx[r] = fmaxf(mx[r], __shfl_xor(mx[r], msk));
      f32x4 sum = (f32x4){0.f,0.f,0.f,0.f};
      #pragma unroll
      for (int nt = 0; nt < 4; nt++)
        #pragma unroll
        for (int r = 0; r < 4; r++) {
          s[mt][nt][r] = __expf(s[mt][nt][r] - mx[r]);
          sum[r] += s[mt][nt][r];
        }
      #pragma unroll
      for (int msk = 1; msk <= 8; msk <<= 1)
        #pragma unroll
        for (int r = 0; r < 4; r++) sum[r] += __shfl_xor(sum[r], msk);
      f32x4 rs;
      #pragma unroll
      for (int r = 0; r < 4; r++) rs[r] = __builtin_amdgcn_rcpf(sum[r]);
      #pragma unroll
      for (int nt = 0; nt < 4; nt++)
        #pragma unroll
        for (int r = 0; r < 4; r++)
          Plds[wv][(mt*16 + quad*4 + r)*72 + nt*16 + ln] =
              __float2bfloat16(s[mt][nt][r] * rs[r]);
    }

    f32x4 o[4][2];
    #pragma unroll
    for (int mt = 0; mt < 4; mt++)
      #pragma unroll
      for (int dt = 0; dt < 2; dt++) o[mt][dt] = (f32x4){0.f,0.f,0.f,0.f};
    #pragma unroll
    for (int ks = 0; ks < 2; ks++) {
      bf16x8 pa[4];
      #pragma unroll
      for (int mt = 0; mt < 4; mt++)
        pa[mt] = *(const bf16x8*)&Plds[wv][(mt*16 + ln)*72 + ks*32 + quad*8];
      #pragma unroll
      for (int dt = 0; dt < 2; dt++) {
        const bf16x8 vb = *(const bf16x8*)(vt + base + (size_t)(dt*16 + ln)*64 + ks*32 + quad*8);
        #pragma unroll
        for (int mt = 0; mt < 4; mt++)
          o[mt][dt] = __builtin_amdgcn_mfma_f32_16x16x32_bf16(pa[mt], vb, o[mt][dt], 0, 0, 0);
      }
    }
    #pragma unroll
    for (int mt = 0; mt < 4; mt++)
      #pragma unroll
      for (int dt = 0; dt < 2; dt++)
        #pragma unroll
        for (int r = 0; r < 4; r++)
          Olds[wv][hh][(mt*16 + quad*4 + r)*36 + dt*16 + ln] =
              __float2bfloat16(o[mt][dt][r]);
  }

  // ---- per-wave LN2 over its 16 output pixels (heads 2wv,2wv+1 local)
  #pragma unroll 4
  for (int i = 0; i < 16; i++) {
    const int p = wv*16 + i, py = p >> 3, px = p & 7, hh = i >> 3;
    const int y2 = wi*8 + py, x2 = wj*8 + px;
    const int y = (y2 + 4) & 255, xx = (x2 + 4) & 255;
    const size_t t = (size_t)b*65536 + y*256 + xx;
    const int c0 = lane * 4;
    const int nn = px*8 + (c0 >> 5), d = c0 & 31;
    union { __hip_bfloat16 h[4]; uint2 u; } ou;
    ou.u = *(const uint2*)&Olds[wv][hh][nn*36 + d];
    float4 xv = ((const float4*)(x + t*256))[lane];
    float sv[4];
    sv[0] = xv.x + __bfloat162float(ou.h[0]);
    sv[1] = xv.y + __bfloat162float(ou.h[1]);
    sv[2] = xv.z + __bfloat162float(ou.h[2]);
    sv[3] = xv.w + __bfloat162float(ou.h[3]);
    float s  = sv[0]+sv[1]+sv[2]+sv[3];
    float sq = sv[0]*sv[0]+sv[1]*sv[1]+sv[2]*sv[2]+sv[3]*sv[3];
    for (int o = 32; o > 0; o >>= 1) { s += __shfl_xor(s, o); sq += __shfl_xor(sq, o); }
    const float mean = s*(1.f/256.f);
    const float rstd = rsqrtf(sq*(1.f/256.f) - mean*mean + 1e-5f);
    union { __hip_bfloat16 h[4]; uint2 u; } ob;
    #pragma unroll
    for (int jj = 0; jj < 4; jj++)
      ob.h[jj] = __float2bfloat16((sv[jj]-mean)*rstd*g2[c0+jj] + b2[c0+jj]);
    *(uint2*)(zb + t*256 + c0) = ob.u;
  }
}

// ---------------- fused MLP: FC1 -> GELU -> FC2 (+bias +zb residual) -> d_out fp32
// 64-token blocks; hidden chunk 128 (8 iters), FC1 wave tile 4x2, FC2 4x4.
// Z [64x256] + H [64x128] LDS-resident (48KB), 8-slot XOR swizzle
// (conflict-free b128 reads); B operands stream from L2.
// PROVEN SHAPE (310us). Lessons: (256,3) -> VGPR 84 cap -> acc2 spills (r2);
// merged FC1||FC2 region -> compiler serializes, 344us (r4); Z direct-from-
// global -> L1 doesn't hold panel, FETCH+70MB + spills, 467us (r5). Keep.
__global__ __launch_bounds__(256, 2) void k_mlp(
    const __hip_bfloat16* __restrict__ zb, const __hip_bfloat16* __restrict__ wf1T,
    const __hip_bfloat16* __restrict__ wf2T, const float* __restrict__ bf1,
    const float* __restrict__ bf2, float* __restrict__ out)
{
  __shared__ __align__(16) __hip_bfloat16 Zlds[64 * 256];   // 32KB, swizzled
  __shared__ __align__(16) __hip_bfloat16 Hlds[64 * 128];   // 16KB, swizzled
  const int tid = threadIdx.x, w = tid >> 6, lane = tid & 63;
  const int quad = lane >> 4, ln = lane & 15;
  const int m0 = blockIdx.x * 64;

  // stage Z: 2048 chunks of 16B via global_load_lds (source pre-swizzled so
  // that LDS holds row-major with elem offset e <- e ^ ((row&7)<<3))
  #pragma unroll
  for (int pass = 0; pass < 8; pass++) {
    const int base = pass*256 + w*64;
    const int L = base + lane;
    const int tok = L >> 5, kc = L & 31;           // kc = 16B chunk within row
    const int kcs = kc ^ (tok & 7);
    gload_lds16(zb + (size_t)(m0 + tok)*256 + kcs*8, Zlds + (size_t)base*8);
  }
  __syncthreads();

  f32x4 acc2[4][4];
  #pragma unroll
  for (int mt = 0; mt < 4; mt++)
    #pragma unroll
    for (int nt = 0; nt < 4; nt++) acc2[mt][nt] = (f32x4){0.f,0.f,0.f,0.f};

  for (int hc = 0; hc < 8; hc++) {
    // ---- FC1 chunk: H[64 x 128], wave w computes hidden cols [w*32, w*32+32)
    f32x4 a1[4][2];
    #pragma unroll
    for (int mt = 0; mt < 4; mt++)
      #pragma unroll
      for (int nt = 0; nt < 2; nt++) a1[mt][nt] = (f32x4){0.f,0.f,0.f,0.f};
    #pragma unroll
    for (int k0 = 0; k0 < 256; k0 += 32) {
      bf16x8 za[4], b1f[2];
      #pragma unroll
      for (int mt = 0; mt < 4; mt++) {
        const int m = mt*16 + ln;
        za[mt] = *(const bf16x8*)&Zlds[m*256 + ((k0 + (quad<<3)) ^ ((m & 7) << 3))];
      }
      #pragma unroll
      for (int nt = 0; nt < 2; nt++) {
        const int n1 = hc*128 + w*32 + nt*16 + ln;
        b1f[nt] = *(const bf16x8*)(wf1T + (size_t)n1*256 + k0 + quad*8);
      }
      #pragma unroll
      for (int mt = 0; mt < 4; mt++)
        #pragma unroll
        for (int nt = 0; nt < 2; nt++)
          a1[mt][nt] = __builtin_amdgcn_mfma_f32_16x16x32_bf16(za[mt], b1f[nt], a1[mt][nt], 0, 0, 0);
    }
    // GELU + swizzled Hlds write
    #pragma unroll
    for (int mt = 0; mt < 4; mt++)
      #pragma unroll
      for (int nt = 0; nt < 2; nt++) {
        const int n = w*32 + nt*16 + ln;
        const float bs = bf1[hc*128 + n];
        #pragma unroll
        for (int r = 0; r < 4; r++) {
          const int m1 = mt*16 + quad*4 + r;
          const float u = gelu_fast(a1[mt][nt][r] + bs);
          Hlds[m1*128 + (n ^ ((m1 & 7) << 3))] = __float2bfloat16(u);
        }
      }
    __syncthreads();
    // ---- FC2 partial: out[64 x 256] += H @ wf2T_chunk, wave w cols [w*64,+64)
    #pragma unroll
    for (int ks = 0; ks < 4; ks++) {
      bf16x8 ha[4];
      #pragma unroll
      for (int mt = 0; mt < 4; mt++) {
        const int m = mt*16 + ln;
        ha[mt] = *(const bf16x8*)&Hlds[m*128 + ((ks*32 + (quad<<3)) ^ ((m & 7) << 3))];
      }
      #pragma unroll
      for (int nt = 0; nt < 4; nt++) {
        const int n2 = w*64 + nt*16 + ln;
        const bf16x8 b2f = *(const bf16x8*)(wf2T + (size_t)n2*1024 + hc*128 + ks*32 + quad*8);
        #pragma unroll
        for (int mt = 0; mt < 4; mt++)
          acc2[mt][nt] = __builtin_amdgcn_mfma_f32_16x16x32_bf16(ha[mt], b2f, acc2[mt][nt], 0, 0, 0);
      }
    }
    __syncthreads();
  }

  // epilogue: + bias + zb residual (from Zlds, swizzled), fp32 out
  #pragma unroll
  for (int mt = 0; mt < 4; mt++) {
    #pragma unroll
    for (int nt = 0; nt < 4; nt++) {
      const int cB = w*64 + nt*16 + ln;
      const float bs = bf2[cB];
      #pragma unroll
      for (int r = 0; r < 4; r++) {
        const int tok = mt*16 + quad*4 + r;
        const float res = __bfloat162float(Zlds[tok*256 + (cB ^ ((tok & 7) << 3))]);
        out[(size_t)(m0 + tok)*256 + cB] = acc2[mt][nt][r] + bs + res;
      }
    }
  }
}

extern "C" void kernel_launch(void* const* d_in, const int* in_sizes, int n_in,
                              void* d_out, int out_size, void* d_ws, size_t ws_size,
                              hipStream_t stream)
{
  (void)in_sizes; (void)n_in; (void)out_size; (void)ws_size;
  const float* x   = (const float*)d_in[0];
  const float* g1  = (const float*)d_in[1];
  const float* b1  = (const float*)d_in[2];
  const float* wq  = (const float*)d_in[3];
  const float* bq  = (const float*)d_in[4];
  const float* wk  = (const float*)d_in[5];
  const float* bk  = (const float*)d_in[6];
  const float* wv  = (const float*)d_in[7];
  const float* bv  = (const float*)d_in[8];
  const float* tbl = (const float*)d_in[9];
  const float* g2  = (const float*)d_in[10];
  const float* b2  = (const float*)d_in[11];
  const float* wf1 = (const float*)d_in[12];
  const float* bf1 = (const float*)d_in[13];
  const float* wf2 = (const float*)d_in[14];
  const float* bf2 = (const float*)d_in[15];

  char* ws = (char*)d_ws;
  const size_t MB = 1024ull*1024ull;
  __hip_bfloat16* qb    = (__hip_bfloat16*)(ws);             // 64MB
  __hip_bfloat16* kb    = (__hip_bfloat16*)(ws + 64*MB);     // 64MB
  __hip_bfloat16* vtb   = (__hip_bfloat16*)(ws + 128*MB);    // 64MB
  __hip_bfloat16* zb    = (__hip_bfloat16*)(ws + 192*MB);    // 64MB
  float*          biasP = (float*)(ws + 256*MB);             // 128KB
  __hip_bfloat16* wqkvT = (__hip_bfloat16*)(ws + 257*MB);    // 384KB
  __hip_bfloat16* wf1T  = (__hip_bfloat16*)(ws + 258*MB);    // 512KB
  __hip_bfloat16* wf2T  = (__hip_bfloat16*)(ws + 259*MB);    // 512KB

  k_pack<<<2816, 256, 0, stream>>>(wq, wk, wv, wf1, wf2, wqkvT, wf1T, wf2T);
  k_bias_pre<<<128, 256, 0, stream>>>(tbl, biasP);
  k_qkv<<<1024, 256, 0, stream>>>(x, g1, b1, wqkvT, bq, bk, bv, qb, kb, vtb);
  k_attn2<<<BW_, 256, 0, stream>>>(qb, kb, vtb, biasP, x, g2, b2, zb);
  k_mlp<<<2048, 256, 0, stream>>>(zb, wf1T, wf2T, bf1, bf2, (float*)d_out);
}